// Round 1
// baseline (141.585 us; speedup 1.0000x reference)
//
#include <hip/hip_runtime.h>
#include <math.h>

#define B 512
#define DG 1024
#define P 1024
#define DA 256

// ---------------------------------------------------------------- utilities
__device__ __forceinline__ float block_reduce_sum(float v, volatile float* red) {
    #pragma unroll
    for (int off = 32; off > 0; off >>= 1) v += __shfl_down(v, off, 64);
    const int lane = threadIdx.x & 63, wid = threadIdx.x >> 6;
    __syncthreads();
    if (lane == 0) red[wid] = v;
    __syncthreads();
    return red[0] + red[1] + red[2] + red[3];
}

// ---------------------------------------------------------------- K1: q_pre = hg @ Wq^T + bq   (512x1024 @ 1024x256)
__global__ __launch_bounds__(256) void k1_qpre(const float* __restrict__ hg,
                                               const float* __restrict__ Wq,
                                               const float* __restrict__ bq,
                                               float* __restrict__ q_pre) {
    __shared__ float As[32][33];
    __shared__ float Bs[32][33];
    const int tid = threadIdx.x;
    const int b0 = blockIdx.x * 32, d0 = blockIdx.y * 32;
    const int tx = tid & 15, ty = tid >> 4;
    float acc[2][2] = {};
    for (int k0 = 0; k0 < DG; k0 += 32) {
        #pragma unroll
        for (int t = 0; t < 4; ++t) {
            int li = tid + t * 256, i = li >> 5, k = li & 31;
            As[i][k] = hg[(b0 + i) * DG + k0 + k];
            Bs[i][k] = Wq[(d0 + i) * DG + k0 + k];
        }
        __syncthreads();
        #pragma unroll
        for (int kk = 0; kk < 32; ++kk) {
            float a0 = As[ty * 2][kk], a1 = As[ty * 2 + 1][kk];
            float w0 = Bs[tx * 2][kk], w1 = Bs[tx * 2 + 1][kk];
            acc[0][0] = fmaf(a0, w0, acc[0][0]);
            acc[0][1] = fmaf(a0, w1, acc[0][1]);
            acc[1][0] = fmaf(a1, w0, acc[1][0]);
            acc[1][1] = fmaf(a1, w1, acc[1][1]);
        }
        __syncthreads();
    }
    #pragma unroll
    for (int i = 0; i < 2; ++i)
        #pragma unroll
        for (int j = 0; j < 2; ++j) {
            int b = b0 + ty * 2 + i, d = d0 + tx * 2 + j;
            q_pre[b * DA + d] = acc[i][j] + bq[d];
        }
}

// ---------------------------------------------------------------- KA: per-b  LN(q_pre) -> q2 = q@Uq^T -> r = q2@Vk -> gr, per-b scalars
__global__ __launch_bounds__(256) void ka_perb(const float* __restrict__ q_pre,
                                               const float* __restrict__ Uq,
                                               const float* __restrict__ Vk,
                                               const float* __restrict__ gq,
                                               const float* __restrict__ bqln,
                                               const float* __restrict__ wk,
                                               const float* __restrict__ bk,
                                               const float* __restrict__ gkln,
                                               const float* __restrict__ bkln,
                                               float* __restrict__ gr,
                                               float* __restrict__ bscal) {
    const int b = blockIdx.x, d = threadIdx.x;
    __shared__ float q_lds[DA];
    __shared__ float q2_lds[DA];
    __shared__ float red[4];

    float x = q_pre[b * DA + d];
    float mu = block_reduce_sum(x, red) * (1.0f / DA);
    float xc = x - mu;
    float var = block_reduce_sum(xc * xc, red) * (1.0f / DA);
    float qv = xc * rsqrtf(var + 1e-5f) * gq[d] + bqln[d];
    q_lds[d] = qv;
    __syncthreads();

    // q2[d] = sum_f q[f] * Uq[d][f]
    float acc = 0.f;
    const float4* Uq4 = reinterpret_cast<const float4*>(Uq + d * DA);
    #pragma unroll 8
    for (int f4 = 0; f4 < DA / 4; ++f4) {
        float4 u4 = Uq4[f4];
        int f = f4 * 4;
        acc = fmaf(q_lds[f], u4.x, acc);
        acc = fmaf(q_lds[f + 1], u4.y, acc);
        acc = fmaf(q_lds[f + 2], u4.z, acc);
        acc = fmaf(q_lds[f + 3], u4.w, acc);
    }
    q2_lds[d] = acc;
    __syncthreads();

    // r[d] = sum_e q2[e] * Vk[e][d]   (coalesced over d)
    float r = 0.f;
    #pragma unroll 8
    for (int e = 0; e < DA; ++e) r = fmaf(q2_lds[e], Vk[e * DA + d], r);

    float gkd = gkln[d];
    gr[b * DA + d] = gkd * r;

    float Wgv = block_reduce_sum(wk[d] * gkd * r, red);
    float Cgv = block_reduce_sum(bk[d] * gkd * r, red);
    float Gv  = block_reduce_sum(gkd * r, red);
    float Bbv = block_reduce_sum(bkln[d] * r, red);
    if (d == 0) {
        bscal[0 * B + b] = Wgv;
        bscal[1 * B + b] = Cgv;
        bscal[2 * B + b] = Gv;
        bscal[3 * B + b] = Bbv;
    }
}

// ---------------------------------------------------------------- KP: per-p LN-stat precompute for k and v
__global__ __launch_bounds__(256) void kp_stats(const float* __restrict__ Ek,
                                                const float* __restrict__ Ev,
                                                const float* __restrict__ bk,
                                                const float* __restrict__ bv,
                                                const float* __restrict__ wk,
                                                const float* __restrict__ wv,
                                                float* __restrict__ pst,
                                                float* __restrict__ scal4) {
    const int p = blockIdx.x, d = threadIdx.x;
    __shared__ float red[4];
    const float inv = 1.0f / DA;
    float ek = Ek[p * DA + d], ev = Ev[p * DA + d];
    float wkd = wk[d], wvd = wv[d];
    float ck = bk[d] + ek, cv = bv[d] + ev;

    float Sck  = block_reduce_sum(ck, red);
    float Sck2 = block_reduce_sum(ck * ck, red);
    float Swck = block_reduce_sum(wkd * ck, red);
    float Scv  = block_reduce_sum(cv, red);
    float Scv2 = block_reduce_sum(cv * cv, red);
    float Swcv = block_reduce_sum(wvd * cv, red);
    float Swk  = block_reduce_sum(wkd, red);
    float Swv  = block_reduce_sum(wvd, red);

    float mwk = Swk * inv, mwv = Swv * inv;
    float mck = Sck * inv, mcv = Scv * inv;
    if (d == 0) {
        pst[0 * P + p] = mck;
        pst[1 * P + p] = Swck * inv - mwk * mck;  // Bk
        pst[2 * P + p] = Sck2 * inv - mck * mck;  // Ck
        pst[3 * P + p] = mcv;
        pst[4 * P + p] = Swcv * inv - mwv * mcv;  // Bv
        pst[5 * P + p] = Scv2 * inv - mcv * mcv;  // Cv
    }
    if (p == 0) {
        float Swk2 = block_reduce_sum(wkd * wkd, red);
        float Swv2 = block_reduce_sum(wvd * wvd, red);
        if (d == 0) {
            scal4[0] = mwk;
            scal4[1] = Swk2 * inv - mwk * mwk;   // A_k
            scal4[2] = mwv;
            scal4[3] = Swv2 * inv - mwv * mwv;   // A_v
        }
    }
}

// ---------------------------------------------------------------- K2: dot = gr @ Ek^T, epilogue -> u = sigmoid(e)  (stored in alpha slot)
__global__ __launch_bounds__(256) void k2_e(const float* __restrict__ gr,
                                            const float* __restrict__ Ek,
                                            const float* __restrict__ desc,
                                            const float* __restrict__ bscal,
                                            const float* __restrict__ pst,
                                            const float* __restrict__ scal4,
                                            float* __restrict__ u_out) {
    __shared__ float As[32][33];
    __shared__ float Bs[64][33];
    const int tid = threadIdx.x;
    const int b0 = blockIdx.x * 32, p0 = blockIdx.y * 64;
    const int tx = tid & 15, ty = tid >> 4;
    float acc[2][4] = {};
    for (int k0 = 0; k0 < DA; k0 += 32) {
        #pragma unroll
        for (int t = 0; t < 4; ++t) {
            int li = tid + t * 256, i = li >> 5, k = li & 31;
            As[i][k] = gr[(b0 + i) * DA + k0 + k];
        }
        #pragma unroll
        for (int t = 0; t < 8; ++t) {
            int li = tid + t * 256, j = li >> 5, k = li & 31;
            Bs[j][k] = Ek[(p0 + j) * DA + k0 + k];
        }
        __syncthreads();
        #pragma unroll
        for (int kk = 0; kk < 32; ++kk) {
            float a0 = As[ty * 2][kk], a1 = As[ty * 2 + 1][kk];
            float e0 = Bs[tx * 4][kk], e1 = Bs[tx * 4 + 1][kk];
            float e2 = Bs[tx * 4 + 2][kk], e3 = Bs[tx * 4 + 3][kk];
            acc[0][0] = fmaf(a0, e0, acc[0][0]);
            acc[0][1] = fmaf(a0, e1, acc[0][1]);
            acc[0][2] = fmaf(a0, e2, acc[0][2]);
            acc[0][3] = fmaf(a0, e3, acc[0][3]);
            acc[1][0] = fmaf(a1, e0, acc[1][0]);
            acc[1][1] = fmaf(a1, e1, acc[1][1]);
            acc[1][2] = fmaf(a1, e2, acc[1][2]);
            acc[1][3] = fmaf(a1, e3, acc[1][3]);
        }
        __syncthreads();
    }
    const float mwk = scal4[0], Ak = scal4[1];
    #pragma unroll
    for (int i = 0; i < 2; ++i) {
        int b = b0 + ty * 2 + i;
        float Wg = bscal[0 * B + b], Cg = bscal[1 * B + b];
        float G = bscal[2 * B + b], Bb = bscal[3 * B + b];
        #pragma unroll
        for (int j = 0; j < 4; ++j) {
            int p = p0 + tx * 4 + j;
            float s = desc[b * P + p];
            float mck = pst[0 * P + p], Bk = pst[1 * P + p], Ck = pst[2 * P + p];
            float var = fmaf(s, fmaf(s, Ak, 2.0f * Bk), Ck);
            float rstd = rsqrtf(var + 1e-5f);
            float mu = fmaf(s, mwk, mck);
            float e = (rstd * (fmaf(s, Wg, Cg) + acc[i][j] - mu * G) + Bb) * 0.0625f;
            u_out[b * P + p] = 1.0f / (1.0f + expf(-e));
        }
    }
}

// ---------------------------------------------------------------- K3: rowsum -> alpha; beta = alpha*rstd_v; c = beta @ Ev + rank-1 terms
__global__ __launch_bounds__(256) void k3_c(const float* __restrict__ desc,
                                            const float* __restrict__ Ev,
                                            const float* __restrict__ pst,
                                            const float* __restrict__ scal4,
                                            const float* __restrict__ wv,
                                            const float* __restrict__ bvv,
                                            const float* __restrict__ gvln,
                                            const float* __restrict__ bvln,
                                            float* __restrict__ out_c,
                                            float* __restrict__ alpha_io) {
    const int tid = threadIdx.x;
    const int b0 = blockIdx.x * 4;
    __shared__ __align__(16) float beta_lds[P * 4];  // [p][bb], 16 KB
    __shared__ float red[4];
    const float mwv = scal4[2], Av = scal4[3];

    // load u (sigmoid outputs written by k2 into the alpha slot)
    float uloc[4][4];
    #pragma unroll
    for (int bb = 0; bb < 4; ++bb)
        #pragma unroll
        for (int j = 0; j < 4; ++j)
            uloc[bb][j] = alpha_io[(b0 + bb) * P + j * 256 + tid];

    float rs[4];
    #pragma unroll
    for (int bb = 0; bb < 4; ++bb)
        rs[bb] = block_reduce_sum(uloc[bb][0] + uloc[bb][1] + uloc[bb][2] + uloc[bb][3], red);

    float SB[4] = {}, SBs[4] = {}, SBm[4] = {}, T[4] = {};
    #pragma unroll
    for (int bb = 0; bb < 4; ++bb) {
        const int b = b0 + bb;
        const float invsum = 1.0f / (rs[bb] + 1e-12f);
        #pragma unroll
        for (int j = 0; j < 4; ++j) {
            const int p = j * 256 + tid;
            float a = uloc[bb][j] * invsum;
            alpha_io[b * P + p] = a;
            float s = desc[b * P + p];
            float mcv = pst[3 * P + p], Bv = pst[4 * P + p], Cv = pst[5 * P + p];
            float var = fmaf(s, fmaf(s, Av, 2.0f * Bv), Cv);
            float rstdv = rsqrtf(var + 1e-5f);
            float beta = a * rstdv;
            beta_lds[p * 4 + bb] = beta;
            SB[bb] += beta;
            SBs[bb] = fmaf(beta, s, SBs[bb]);
            SBm[bb] = fmaf(beta, fmaf(s, mwv, mcv), SBm[bb]);
            T[bb] += a;
        }
    }
    // block-wide scalar reductions (returns value to all threads); also syncs beta_lds
    float SBr[4], SBsr[4], SBmr[4], Tr[4];
    #pragma unroll
    for (int bb = 0; bb < 4; ++bb) {
        SBr[bb]  = block_reduce_sum(SB[bb], red);
        SBsr[bb] = block_reduce_sum(SBs[bb], red);
        SBmr[bb] = block_reduce_sum(SBm[bb], red);
        Tr[bb]   = block_reduce_sum(T[bb], red);
    }

    // c-part GEMM: acc[bb] = sum_p beta[p][bb] * Ev[p][d]
    const float4* bl4 = reinterpret_cast<const float4*>(beta_lds);
    float a0 = 0.f, a1 = 0.f, a2 = 0.f, a3 = 0.f;
    for (int p = 0; p < P; p += 2) {
        float4 x0 = bl4[p];
        float4 x1 = bl4[p + 1];
        float e0 = Ev[p * DA + tid];
        float e1 = Ev[(p + 1) * DA + tid];
        a0 = fmaf(x0.x, e0, a0);
        a1 = fmaf(x0.y, e0, a1);
        a2 = fmaf(x0.z, e0, a2);
        a3 = fmaf(x0.w, e0, a3);
        a0 = fmaf(x1.x, e1, a0);
        a1 = fmaf(x1.y, e1, a1);
        a2 = fmaf(x1.z, e1, a2);
        a3 = fmaf(x1.w, e1, a3);
    }
    float accd[4] = {a0, a1, a2, a3};

    const float gvd = gvln[tid], wvd = wv[tid], bvd = bvv[tid], blnd = bvln[tid];
    #pragma unroll
    for (int bb = 0; bb < 4; ++bb) {
        float c = gvd * (wvd * SBsr[bb] + bvd * SBr[bb] + accd[bb] - SBmr[bb]) + blnd * Tr[bb];
        out_c[(b0 + bb) * DA + tid] = c;
    }
}

// ---------------------------------------------------------------- launch
extern "C" void kernel_launch(void* const* d_in, const int* in_sizes, int n_in,
                              void* d_out, int out_size, void* d_ws, size_t ws_size,
                              hipStream_t stream) {
    (void)in_sizes; (void)n_in; (void)out_size; (void)ws_size;
    const float* hg   = (const float*)d_in[0];
    const float* desc = (const float*)d_in[1];
    const float* Wq   = (const float*)d_in[2];
    const float* bq   = (const float*)d_in[3];
    const float* wk   = (const float*)d_in[4];
    const float* bk   = (const float*)d_in[5];
    const float* wv   = (const float*)d_in[6];
    const float* bv   = (const float*)d_in[7];
    const float* Ek   = (const float*)d_in[8];
    const float* Ev   = (const float*)d_in[9];
    const float* Uq   = (const float*)d_in[10];
    const float* Vk   = (const float*)d_in[11];
    const float* gq   = (const float*)d_in[12];
    const float* bqln = (const float*)d_in[13];
    const float* gk   = (const float*)d_in[14];
    const float* bkln = (const float*)d_in[15];
    const float* gv   = (const float*)d_in[16];
    const float* bvln = (const float*)d_in[17];

    float* out = (float*)d_out;
    float* out_c = out;              // B*DA floats
    float* out_alpha = out + B * DA; // B*P floats (used as u-scratch by k2, normalized by k3)

    float* ws = (float*)d_ws;
    float* q_pre = ws;               // 131072
    float* gr    = ws + 131072;      // 131072
    float* bscal = ws + 262144;      // 2048
    float* pst   = ws + 264192;      // 6144
    float* scal4 = ws + 270336;      // 4

    k1_qpre<<<dim3(16, 8), 256, 0, stream>>>(hg, Wq, bq, q_pre);
    kp_stats<<<1024, 256, 0, stream>>>(Ek, Ev, bk, bv, wk, wv, pst, scal4);
    ka_perb<<<512, 256, 0, stream>>>(q_pre, Uq, Vk, gq, bqln, wk, bk, gk, bkln, gr, bscal);
    k2_e<<<dim3(16, 16), 256, 0, stream>>>(gr, Ek, desc, bscal, pst, scal4, out_alpha);
    k3_c<<<128, 256, 0, stream>>>(desc, Ev, pst, scal4, wv, bv, gv, bvln, out_c, out_alpha);
}

// Round 2
// 74.188 us; speedup vs baseline: 1.9085x; 1.9085x over previous
//
#include <hip/hip_runtime.h>
#include <math.h>

#define B 512
#define DG 1024
#define P 1024
#define DA 256

// ---------------------------------------------------------------- utilities
__device__ __forceinline__ float block_reduce_sum(float v, volatile float* red) {
    #pragma unroll
    for (int off = 32; off > 0; off >>= 1) v += __shfl_down(v, off, 64);
    const int lane = threadIdx.x & 63, wid = threadIdx.x >> 6;
    __syncthreads();
    if (lane == 0) red[wid] = v;
    __syncthreads();
    return red[0] + red[1] + red[2] + red[3];
}

// ---------------------------------------------------------------- KA mega-kernel (layer 1, all independent):
//  bi==0        : k0v  - vec4[4][256]: wvec/cvec/gvec/bbvec via two chained matvecs (no M needed)
//  bi in [1,257): k1   - q_pre partial GEMM  hg(512x1024) @ Wq^T(1024x256), 32x64 tiles, split-K 4
//  bi in [257,321): k0a- Mg[f][d] = gk[d] * sum_e Uq[e,f] Vk[e,d], 32x32 tiles
//  bi in [321,1345): kp- per-p LN stats for k and v
__global__ __launch_bounds__(256) void KA(const float* __restrict__ hg, const float* __restrict__ Wq,
                                          const float* __restrict__ Uq, const float* __restrict__ Vk,
                                          const float* __restrict__ Ek, const float* __restrict__ Ev,
                                          const float* __restrict__ wk, const float* __restrict__ bk,
                                          const float* __restrict__ wv, const float* __restrict__ bv,
                                          const float* __restrict__ gk, const float* __restrict__ bkln,
                                          float* __restrict__ qp, float* __restrict__ Mg,
                                          float* __restrict__ pst, float* __restrict__ scal4,
                                          float* __restrict__ vec4) {
    __shared__ __align__(16) float lds[3264];
    __shared__ float red[4];
    const int tid = threadIdx.x;
    const int bi = blockIdx.x;

    if (bi == 0) {
        // ---- k0v: tmp[e][4] = sum_d Vk[e,d]*w4[j][d]; vec4[j][f] = sum_e Uq[e,f]*tmp[e][j]
        float* w4  = lds;          // [4][256]
        float* tmp = lds + 1024;   // [256][4]
        float gkd = gk[tid];
        w4[0 * 256 + tid] = wk[tid] * gkd;
        w4[1 * 256 + tid] = bk[tid] * gkd;
        w4[2 * 256 + tid] = gkd;
        w4[3 * 256 + tid] = bkln[tid];
        __syncthreads();
        const int dl = tid & 15, eg = tid >> 4;
        for (int eb = 0; eb < 16; ++eb) {
            int e = eb * 16 + eg;
            float p0 = 0.f, p1 = 0.f, p2 = 0.f, p3 = 0.f;
            #pragma unroll
            for (int t = 0; t < 16; ++t) {
                int d = dl + t * 16;
                float v = Vk[e * DA + d];
                p0 = fmaf(v, w4[d], p0);
                p1 = fmaf(v, w4[256 + d], p1);
                p2 = fmaf(v, w4[512 + d], p2);
                p3 = fmaf(v, w4[768 + d], p3);
            }
            #pragma unroll
            for (int m = 8; m > 0; m >>= 1) {
                p0 += __shfl_xor(p0, m, 16);
                p1 += __shfl_xor(p1, m, 16);
                p2 += __shfl_xor(p2, m, 16);
                p3 += __shfl_xor(p3, m, 16);
            }
            if (dl == 0) {
                tmp[e * 4 + 0] = p0; tmp[e * 4 + 1] = p1;
                tmp[e * 4 + 2] = p2; tmp[e * 4 + 3] = p3;
            }
        }
        __syncthreads();
        float a0 = 0.f, a1 = 0.f, a2 = 0.f, a3 = 0.f;
        for (int e = 0; e < 256; ++e) {
            float u = Uq[e * DA + tid];   // coalesced
            a0 = fmaf(u, tmp[e * 4 + 0], a0);
            a1 = fmaf(u, tmp[e * 4 + 1], a1);
            a2 = fmaf(u, tmp[e * 4 + 2], a2);
            a3 = fmaf(u, tmp[e * 4 + 3], a3);
        }
        vec4[tid] = a0; vec4[256 + tid] = a1; vec4[512 + tid] = a2; vec4[768 + tid] = a3;
    } else if (bi < 257) {
        // ---- k1: qp[ks] = hg @ Wq^T partial over K-chunk, 32x64 tile, 2x4 acc, B via b128
        float* As = lds;           // [32][33]  (A = hg rows, [m][k])
        float* Bs = lds + 1056;    // [32][68]  (B = Wq transposed to [k][n])
        const int b2 = bi - 1;
        const int mt = b2 & 15, nt = (b2 >> 4) & 3, ks = b2 >> 6;
        const int b0 = mt * 32, d0 = nt * 64, kc = ks * 256;
        const int tx = tid & 15, ty = tid >> 4;
        float acc[2][4] = {};
        const int sm = tid >> 3, sk4 = (tid & 7) * 4;
        for (int kt = 0; kt < 256; kt += 32) {
            const int kg = kc + kt;
            float4 av = *reinterpret_cast<const float4*>(hg + (b0 + sm) * DG + kg + sk4);
            As[sm * 33 + sk4 + 0] = av.x; As[sm * 33 + sk4 + 1] = av.y;
            As[sm * 33 + sk4 + 2] = av.z; As[sm * 33 + sk4 + 3] = av.w;
            #pragma unroll
            for (int s = 0; s < 2; ++s) {
                int id = tid + s * 256;
                int n = id >> 3, k4 = (id & 7) * 4;
                float4 w4v = *reinterpret_cast<const float4*>(Wq + (d0 + n) * DG + kg + k4);
                Bs[(k4 + 0) * 68 + n] = w4v.x; Bs[(k4 + 1) * 68 + n] = w4v.y;
                Bs[(k4 + 2) * 68 + n] = w4v.z; Bs[(k4 + 3) * 68 + n] = w4v.w;
            }
            __syncthreads();
            #pragma unroll
            for (int kk = 0; kk < 32; ++kk) {
                float a0 = As[(ty * 2 + 0) * 33 + kk];
                float a1 = As[(ty * 2 + 1) * 33 + kk];
                float4 bv4 = *reinterpret_cast<const float4*>(&Bs[kk * 68 + tx * 4]);
                acc[0][0] = fmaf(a0, bv4.x, acc[0][0]); acc[0][1] = fmaf(a0, bv4.y, acc[0][1]);
                acc[0][2] = fmaf(a0, bv4.z, acc[0][2]); acc[0][3] = fmaf(a0, bv4.w, acc[0][3]);
                acc[1][0] = fmaf(a1, bv4.x, acc[1][0]); acc[1][1] = fmaf(a1, bv4.y, acc[1][1]);
                acc[1][2] = fmaf(a1, bv4.z, acc[1][2]); acc[1][3] = fmaf(a1, bv4.w, acc[1][3]);
            }
            __syncthreads();
        }
        float* outp = qp + ks * (B * DA);
        #pragma unroll
        for (int i = 0; i < 2; ++i) {
            float4 o;
            o.x = acc[i][0]; o.y = acc[i][1]; o.z = acc[i][2]; o.w = acc[i][3];
            *reinterpret_cast<float4*>(outp + (b0 + ty * 2 + i) * DA + d0 + tx * 4) = o;
        }
    } else if (bi < 321) {
        // ---- k0a: Mg[f][d] = gk[d] * sum_e Uq[e,f]*Vk[e,d], 32x32 tile 2x2, both operands [k][out]
        float* As = lds;          // [32][33]  [k][f]
        float* Bs = lds + 1056;   // [32][33]  [k][d]
        const int b2 = bi - 257;
        const int ft0 = (b2 & 7) * 32, dt0 = (b2 >> 3) * 32;
        const int tx = tid & 15, ty = tid >> 4;
        float acc[2][2] = {};
        const int sk = tid >> 3, sf4 = (tid & 7) * 4;
        for (int kt = 0; kt < 256; kt += 32) {
            float4 uv = *reinterpret_cast<const float4*>(Uq + (kt + sk) * DA + ft0 + sf4);
            As[sk * 33 + sf4 + 0] = uv.x; As[sk * 33 + sf4 + 1] = uv.y;
            As[sk * 33 + sf4 + 2] = uv.z; As[sk * 33 + sf4 + 3] = uv.w;
            float4 vv = *reinterpret_cast<const float4*>(Vk + (kt + sk) * DA + dt0 + sf4);
            Bs[sk * 33 + sf4 + 0] = vv.x; Bs[sk * 33 + sf4 + 1] = vv.y;
            Bs[sk * 33 + sf4 + 2] = vv.z; Bs[sk * 33 + sf4 + 3] = vv.w;
            __syncthreads();
            #pragma unroll
            for (int kk = 0; kk < 32; ++kk) {
                float a0 = As[kk * 33 + ty * 2 + 0], a1 = As[kk * 33 + ty * 2 + 1];
                float c0 = Bs[kk * 33 + tx * 2 + 0], c1 = Bs[kk * 33 + tx * 2 + 1];
                acc[0][0] = fmaf(a0, c0, acc[0][0]); acc[0][1] = fmaf(a0, c1, acc[0][1]);
                acc[1][0] = fmaf(a1, c0, acc[1][0]); acc[1][1] = fmaf(a1, c1, acc[1][1]);
            }
            __syncthreads();
        }
        #pragma unroll
        for (int i = 0; i < 2; ++i)
            #pragma unroll
            for (int j = 0; j < 2; ++j) {
                int d = dt0 + tx * 2 + j;
                Mg[(ft0 + ty * 2 + i) * DA + d] = acc[i][j] * gk[d];
            }
    } else {
        // ---- kp: per-p LN-stat precompute for k and v
        const int p = bi - 321, d = tid;
        const float inv = 1.0f / DA;
        float ek = Ek[p * DA + d], ev = Ev[p * DA + d];
        float wkd = wk[d], wvd = wv[d];
        float ck = bk[d] + ek, cv = bv[d] + ev;

        float Sck  = block_reduce_sum(ck, red);
        float Sck2 = block_reduce_sum(ck * ck, red);
        float Swck = block_reduce_sum(wkd * ck, red);
        float Scv  = block_reduce_sum(cv, red);
        float Scv2 = block_reduce_sum(cv * cv, red);
        float Swcv = block_reduce_sum(wvd * cv, red);
        float Swk  = block_reduce_sum(wkd, red);
        float Swv  = block_reduce_sum(wvd, red);

        float mwk = Swk * inv, mwv = Swv * inv;
        float mck = Sck * inv, mcv = Scv * inv;
        if (d == 0) {
            pst[0 * P + p] = mck;
            pst[1 * P + p] = Swck * inv - mwk * mck;  // Bk
            pst[2 * P + p] = Sck2 * inv - mck * mck;  // Ck
            pst[3 * P + p] = mcv;
            pst[4 * P + p] = Swcv * inv - mwv * mcv;  // Bv
            pst[5 * P + p] = Scv2 * inv - mcv * mcv;  // Cv
        }
        if (p == 0) {
            float Swk2 = block_reduce_sum(wkd * wkd, red);
            float Swv2 = block_reduce_sum(wvd * wvd, red);
            if (d == 0) {
                scal4[0] = mwk;
                scal4[1] = Swk2 * inv - mwk * mwk;   // A_k
                scal4[2] = mwv;
                scal4[3] = Swv2 * inv - mwv * mwv;   // A_v
            }
        }
    }
}

// ---------------------------------------------------------------- KB: N[f][p] = sum_d Mg[f,d] * Ek[p,d]  (256x1024, K=256)
__global__ __launch_bounds__(256) void KB(const float* __restrict__ Mg, const float* __restrict__ Ek,
                                          float* __restrict__ Nm) {
    __shared__ float As[32 * 33];  // Mg [m][k]
    __shared__ float Bs[32 * 33];  // Ek transposed -> [k][n]
    const int tid = threadIdx.x;
    const int ft0 = (blockIdx.x & 7) * 32, pt0 = (blockIdx.x >> 3) * 32;
    const int tx = tid & 15, ty = tid >> 4;
    float acc[2][2] = {};
    const int sr = tid >> 3, sc4 = (tid & 7) * 4;
    for (int kt = 0; kt < 256; kt += 32) {
        float4 mv = *reinterpret_cast<const float4*>(Mg + (ft0 + sr) * DA + kt + sc4);
        As[sr * 33 + sc4 + 0] = mv.x; As[sr * 33 + sc4 + 1] = mv.y;
        As[sr * 33 + sc4 + 2] = mv.z; As[sr * 33 + sc4 + 3] = mv.w;
        float4 evv = *reinterpret_cast<const float4*>(Ek + (pt0 + sr) * DA + kt + sc4);
        Bs[(sc4 + 0) * 33 + sr] = evv.x; Bs[(sc4 + 1) * 33 + sr] = evv.y;
        Bs[(sc4 + 2) * 33 + sr] = evv.z; Bs[(sc4 + 3) * 33 + sr] = evv.w;
        __syncthreads();
        #pragma unroll
        for (int kk = 0; kk < 32; ++kk) {
            float a0 = As[(ty * 2 + 0) * 33 + kk], a1 = As[(ty * 2 + 1) * 33 + kk];
            float c0 = Bs[kk * 33 + tx * 2 + 0], c1 = Bs[kk * 33 + tx * 2 + 1];
            acc[0][0] = fmaf(a0, c0, acc[0][0]); acc[0][1] = fmaf(a0, c1, acc[0][1]);
            acc[1][0] = fmaf(a1, c0, acc[1][0]); acc[1][1] = fmaf(a1, c1, acc[1][1]);
        }
        __syncthreads();
    }
    #pragma unroll
    for (int i = 0; i < 2; ++i)
        #pragma unroll
        for (int j = 0; j < 2; ++j)
            Nm[(ft0 + ty * 2 + i) * P + pt0 + tx * 2 + j] = acc[i][j];
}

// ---------------------------------------------------------------- KC: per-b  LN(sum qp + bq) -> q; 4 scalar dots vs vec4
__global__ __launch_bounds__(256) void KC(const float* __restrict__ qp, const float* __restrict__ bq,
                                          const float* __restrict__ gq, const float* __restrict__ bqln,
                                          const float* __restrict__ vec4, float* __restrict__ qout,
                                          float* __restrict__ bscal) {
    __shared__ float red[4];
    const int b = blockIdx.x, d = threadIdx.x;
    float x = bq[d];
    #pragma unroll
    for (int ks = 0; ks < 4; ++ks) x += qp[ks * (B * DA) + b * DA + d];
    float mu = block_reduce_sum(x, red) * (1.0f / DA);
    float xc = x - mu;
    float var = block_reduce_sum(xc * xc, red) * (1.0f / DA);
    float qv = xc * rsqrtf(var + 1e-5f) * gq[d] + bqln[d];
    qout[b * DA + d] = qv;
    float Wg = block_reduce_sum(qv * vec4[d], red);
    float Cg = block_reduce_sum(qv * vec4[256 + d], red);
    float G  = block_reduce_sum(qv * vec4[512 + d], red);
    float Bb = block_reduce_sum(qv * vec4[768 + d], red);
    if (d == 0) {
        bscal[b] = Wg; bscal[B + b] = Cg; bscal[2 * B + b] = G; bscal[3 * B + b] = Bb;
    }
}

// ---------------------------------------------------------------- KD: e = q @ N + epilogue -> u = sigmoid(e)  (512x1024, K=256)
__global__ __launch_bounds__(256) void KD(const float* __restrict__ q, const float* __restrict__ Nm,
                                          const float* __restrict__ desc, const float* __restrict__ bscal,
                                          const float* __restrict__ pst, const float* __restrict__ scal4,
                                          float* __restrict__ u_out) {
    __shared__ __align__(16) float As[32 * 33];  // q [m][k]
    __shared__ __align__(16) float Bs[32 * 68];  // N [k][n], b128 reads
    const int tid = threadIdx.x;
    const int b0 = (blockIdx.x & 15) * 32, p0 = (blockIdx.x >> 4) * 64;
    const int tx = tid & 15, ty = tid >> 4;
    float acc[2][4] = {};
    const int sm = tid >> 3, sk4 = (tid & 7) * 4;
    const int bk_ = tid >> 4, bn4 = (tid & 15) * 4;
    for (int kt = 0; kt < 256; kt += 32) {
        float4 qv4 = *reinterpret_cast<const float4*>(q + (b0 + sm) * DA + kt + sk4);
        As[sm * 33 + sk4 + 0] = qv4.x; As[sm * 33 + sk4 + 1] = qv4.y;
        As[sm * 33 + sk4 + 2] = qv4.z; As[sm * 33 + sk4 + 3] = qv4.w;
        #pragma unroll
        for (int s = 0; s < 2; ++s) {
            int k = bk_ + s * 16;
            float4 nv = *reinterpret_cast<const float4*>(Nm + (kt + k) * P + p0 + bn4);
            *reinterpret_cast<float4*>(&Bs[k * 68 + bn4]) = nv;
        }
        __syncthreads();
        #pragma unroll
        for (int kk = 0; kk < 32; ++kk) {
            float a0 = As[(ty * 2 + 0) * 33 + kk];
            float a1 = As[(ty * 2 + 1) * 33 + kk];
            float4 bv4 = *reinterpret_cast<const float4*>(&Bs[kk * 68 + tx * 4]);
            acc[0][0] = fmaf(a0, bv4.x, acc[0][0]); acc[0][1] = fmaf(a0, bv4.y, acc[0][1]);
            acc[0][2] = fmaf(a0, bv4.z, acc[0][2]); acc[0][3] = fmaf(a0, bv4.w, acc[0][3]);
            acc[1][0] = fmaf(a1, bv4.x, acc[1][0]); acc[1][1] = fmaf(a1, bv4.y, acc[1][1]);
            acc[1][2] = fmaf(a1, bv4.z, acc[1][2]); acc[1][3] = fmaf(a1, bv4.w, acc[1][3]);
        }
        __syncthreads();
    }
    const float mwk = scal4[0], Ak = scal4[1];
    #pragma unroll
    for (int i = 0; i < 2; ++i) {
        int b = b0 + ty * 2 + i;
        float Wg = bscal[b], Cg = bscal[B + b], G = bscal[2 * B + b], Bb = bscal[3 * B + b];
        float4 o;
        float* oc = &o.x;
        #pragma unroll
        for (int j = 0; j < 4; ++j) {
            int p = p0 + tx * 4 + j;
            float s = desc[b * P + p];
            float mck = pst[p], Bk = pst[P + p], Ck = pst[2 * P + p];
            float var = fmaf(s, fmaf(s, Ak, 2.0f * Bk), Ck);
            float rstd = rsqrtf(var + 1e-5f);
            float mu = fmaf(s, mwk, mck);
            float e = (rstd * (fmaf(s, Wg, Cg) + acc[i][j] - mu * G) + Bb) * 0.0625f;
            oc[j] = 1.0f / (1.0f + expf(-e));
        }
        *reinterpret_cast<float4*>(u_out + b * P + p0 + tx * 4) = o;
    }
}

// ---------------------------------------------------------------- KE: alpha = u/rowsum (in place), beta = alpha*rstd_v, per-b scalars
__global__ __launch_bounds__(256) void KE(const float* __restrict__ desc, const float* __restrict__ pst,
                                          const float* __restrict__ scal4, float* __restrict__ alpha_io,
                                          float* __restrict__ beta, float* __restrict__ bscal2) {
    __shared__ float red[4];
    const int b = blockIdx.x, tid = threadIdx.x;
    float u[4];
    #pragma unroll
    for (int j = 0; j < 4; ++j) u[j] = alpha_io[b * P + j * 256 + tid];
    float S = block_reduce_sum(u[0] + u[1] + u[2] + u[3], red);
    float invS = 1.0f / (S + 1e-12f);
    float T = S * invS;
    const float mwv = scal4[2], Av = scal4[3];
    float SB = 0.f, SBs = 0.f, SBm = 0.f;
    #pragma unroll
    for (int j = 0; j < 4; ++j) {
        int p = j * 256 + tid;
        float a = u[j] * invS;
        alpha_io[b * P + p] = a;
        float s = desc[b * P + p];
        float mcv = pst[3 * P + p], Bv = pst[4 * P + p], Cv = pst[5 * P + p];
        float var = fmaf(s, fmaf(s, Av, 2.0f * Bv), Cv);
        float rstdv = rsqrtf(var + 1e-5f);
        float bt = a * rstdv;
        beta[b * P + p] = bt;
        SB += bt;
        SBs = fmaf(bt, s, SBs);
        SBm = fmaf(bt, fmaf(s, mwv, mcv), SBm);
    }
    SB  = block_reduce_sum(SB, red);
    SBs = block_reduce_sum(SBs, red);
    SBm = block_reduce_sum(SBm, red);
    if (tid == 0) {
        bscal2[b] = SB; bscal2[B + b] = SBs; bscal2[2 * B + b] = SBm; bscal2[3 * B + b] = T;
    }
}

// ---------------------------------------------------------------- KF: cpart[ks] = beta @ Ev partial (512x256, K-chunk 256)
__global__ __launch_bounds__(256) void KF(const float* __restrict__ beta, const float* __restrict__ Ev,
                                          float* __restrict__ cpart) {
    __shared__ __align__(16) float As[32 * 33];  // beta [m][k]
    __shared__ __align__(16) float Bs[32 * 68];  // Ev [k][n], b128 reads
    const int tid = threadIdx.x;
    const int mt = blockIdx.x & 15, nt = (blockIdx.x >> 4) & 3, ks = blockIdx.x >> 6;
    const int b0 = mt * 32, d0 = nt * 64, kc = ks * 256;
    const int tx = tid & 15, ty = tid >> 4;
    float acc[2][4] = {};
    const int sm = tid >> 3, sk4 = (tid & 7) * 4;
    const int bk_ = tid >> 4, bn4 = (tid & 15) * 4;
    for (int kt = 0; kt < 256; kt += 32) {
        const int kg = kc + kt;
        float4 av = *reinterpret_cast<const float4*>(beta + (b0 + sm) * P + kg + sk4);
        As[sm * 33 + sk4 + 0] = av.x; As[sm * 33 + sk4 + 1] = av.y;
        As[sm * 33 + sk4 + 2] = av.z; As[sm * 33 + sk4 + 3] = av.w;
        #pragma unroll
        for (int s = 0; s < 2; ++s) {
            int k = bk_ + s * 16;
            float4 evv = *reinterpret_cast<const float4*>(Ev + (kg + k) * DA + d0 + bn4);
            *reinterpret_cast<float4*>(&Bs[k * 68 + bn4]) = evv;
        }
        __syncthreads();
        #pragma unroll
        for (int kk = 0; kk < 32; ++kk) {
            float a0 = As[(ty * 2 + 0) * 33 + kk];
            float a1 = As[(ty * 2 + 1) * 33 + kk];
            float4 bv4 = *reinterpret_cast<const float4*>(&Bs[kk * 68 + tx * 4]);
            acc[0][0] = fmaf(a0, bv4.x, acc[0][0]); acc[0][1] = fmaf(a0, bv4.y, acc[0][1]);
            acc[0][2] = fmaf(a0, bv4.z, acc[0][2]); acc[0][3] = fmaf(a0, bv4.w, acc[0][3]);
            acc[1][0] = fmaf(a1, bv4.x, acc[1][0]); acc[1][1] = fmaf(a1, bv4.y, acc[1][1]);
            acc[1][2] = fmaf(a1, bv4.z, acc[1][2]); acc[1][3] = fmaf(a1, bv4.w, acc[1][3]);
        }
        __syncthreads();
    }
    float* outp = cpart + ks * (B * DA);
    #pragma unroll
    for (int i = 0; i < 2; ++i) {
        float4 o;
        o.x = acc[i][0]; o.y = acc[i][1]; o.z = acc[i][2]; o.w = acc[i][3];
        *reinterpret_cast<float4*>(outp + (b0 + ty * 2 + i) * DA + d0 + tx * 4) = o;
    }
}

// ---------------------------------------------------------------- KG: c = gv*(wv*SBs + bv*SB + sum_ks cpart - SBm) + bvln*T
__global__ __launch_bounds__(256) void KG(const float* __restrict__ cpart, const float* __restrict__ bscal2,
                                          const float* __restrict__ gv, const float* __restrict__ wv,
                                          const float* __restrict__ bv, const float* __restrict__ bvln,
                                          float* __restrict__ out_c) {
    const int b = blockIdx.x, d = threadIdx.x;
    float s = 0.f;
    #pragma unroll
    for (int ks = 0; ks < 4; ++ks) s += cpart[ks * (B * DA) + b * DA + d];
    float SB = bscal2[b], SBs = bscal2[B + b], SBm = bscal2[2 * B + b], T = bscal2[3 * B + b];
    out_c[b * DA + d] = gv[d] * (wv[d] * SBs + bv[d] * SB + s - SBm) + bvln[d] * T;
}

// ---------------------------------------------------------------- launch
extern "C" void kernel_launch(void* const* d_in, const int* in_sizes, int n_in,
                              void* d_out, int out_size, void* d_ws, size_t ws_size,
                              hipStream_t stream) {
    (void)in_sizes; (void)n_in; (void)out_size; (void)ws_size;
    const float* hg   = (const float*)d_in[0];
    const float* desc = (const float*)d_in[1];
    const float* Wq   = (const float*)d_in[2];
    const float* bq   = (const float*)d_in[3];
    const float* wk   = (const float*)d_in[4];
    const float* bk   = (const float*)d_in[5];
    const float* wv   = (const float*)d_in[6];
    const float* bv   = (const float*)d_in[7];
    const float* Ek   = (const float*)d_in[8];
    const float* Ev   = (const float*)d_in[9];
    const float* Uq   = (const float*)d_in[10];
    const float* Vk   = (const float*)d_in[11];
    const float* gq   = (const float*)d_in[12];
    const float* bqln = (const float*)d_in[13];
    const float* gk   = (const float*)d_in[14];
    const float* bkln = (const float*)d_in[15];
    const float* gv   = (const float*)d_in[16];
    const float* bvln = (const float*)d_in[17];

    float* out = (float*)d_out;
    float* out_c = out;              // B*DA
    float* out_alpha = out + B * DA; // B*P (u written by KD, normalized in place by KE)

    float* ws = (float*)d_ws;
    float* qp    = ws;                 // 4*131072 (k1 partials; REUSED later as cpart)
    float* cpart = ws;                 //   alias: qp dead after KC, cpart written in KF
    float* q     = ws + 524288;        // 131072
    float* Mg    = ws + 655360;        // 65536
    float* Nm    = ws + 720896;        // 262144
    float* beta  = ws + 983040;        // 524288
    float* vec4  = ws + 1507328;       // 1024
    float* bscal = ws + 1508352;       // 2048
    float* bscal2= ws + 1510400;       // 2048
    float* pst   = ws + 1512448;       // 6144
    float* scal4 = ws + 1518592;       // 4

    KA<<<1345, 256, 0, stream>>>(hg, Wq, Uq, Vk, Ek, Ev, wk, bk, wv, bv, gk, bkln,
                                 qp, Mg, pst, scal4, vec4);
    KB<<<256, 256, 0, stream>>>(Mg, Ek, Nm);
    KC<<<512, 256, 0, stream>>>(qp, bq, gq, bqln, vec4, q, bscal);
    KD<<<256, 256, 0, stream>>>(q, Nm, desc, bscal, pst, scal4, out_alpha);
    KE<<<512, 256, 0, stream>>>(desc, pst, scal4, out_alpha, beta, bscal2);
    KF<<<256, 256, 0, stream>>>(beta, Ev, cpart);
    KG<<<512, 256, 0, stream>>>(cpart, bscal2, gv, wv, bv, bvln, out_c);
}

// Round 3
// 60.743 us; speedup vs baseline: 2.3309x; 1.2214x over previous
//
#include <hip/hip_runtime.h>
#include <math.h>

#define B 512
#define DG 1024
#define P 1024
#define DA 256
#define LDP 68   // padded leading dim for [32][LDP] stage tiles (272B rows, 16B-aligned)

// ---------------------------------------------------------------- utilities
__device__ __forceinline__ float block_reduce_sum(float v, volatile float* red) {
    #pragma unroll
    for (int off = 32; off > 0; off >>= 1) v += __shfl_down(v, off, 64);
    const int lane = threadIdx.x & 63, wid = threadIdx.x >> 6;
    __syncthreads();
    if (lane == 0) red[wid] = v;
    __syncthreads();
    return red[0] + red[1] + red[2] + red[3];
}

#define FMA16(a4, b4, acc)                                   \
    acc[0][0] = fmaf(a4.x, b4.x, acc[0][0]);                 \
    acc[0][1] = fmaf(a4.x, b4.y, acc[0][1]);                 \
    acc[0][2] = fmaf(a4.x, b4.z, acc[0][2]);                 \
    acc[0][3] = fmaf(a4.x, b4.w, acc[0][3]);                 \
    acc[1][0] = fmaf(a4.y, b4.x, acc[1][0]);                 \
    acc[1][1] = fmaf(a4.y, b4.y, acc[1][1]);                 \
    acc[1][2] = fmaf(a4.y, b4.z, acc[1][2]);                 \
    acc[1][3] = fmaf(a4.y, b4.w, acc[1][3]);                 \
    acc[2][0] = fmaf(a4.z, b4.x, acc[2][0]);                 \
    acc[2][1] = fmaf(a4.z, b4.y, acc[2][1]);                 \
    acc[2][2] = fmaf(a4.z, b4.z, acc[2][2]);                 \
    acc[2][3] = fmaf(a4.z, b4.w, acc[2][3]);                 \
    acc[3][0] = fmaf(a4.w, b4.x, acc[3][0]);                 \
    acc[3][1] = fmaf(a4.w, b4.y, acc[3][1]);                 \
    acc[3][2] = fmaf(a4.w, b4.z, acc[3][2]);                 \
    acc[3][3] = fmaf(a4.w, b4.w, acc[3][3]);

// ---------------------------------------------------------------- KA mega-kernel:
//  bi in [0,256)    : k1  - qp[ks] partial of hg(512x1024)@Wq^T, 64x64 tile, 4x4 acc, KS=8
//  bi in [256,320)  : tr  - UqT[f][e] = Uq[e][f]
//  bi in [320,1344) : kp  - per-p LN stats for k and v
__global__ __launch_bounds__(256) void KA(const float* __restrict__ hg, const float* __restrict__ Wq,
                                          const float* __restrict__ Uq,
                                          const float* __restrict__ Ek, const float* __restrict__ Ev,
                                          const float* __restrict__ wk, const float* __restrict__ bk,
                                          const float* __restrict__ wv, const float* __restrict__ bv,
                                          float* __restrict__ qp, float* __restrict__ UqT,
                                          float* __restrict__ pst, float* __restrict__ scal4) {
    __shared__ __align__(16) float sA[32 * LDP];
    __shared__ __align__(16) float sB[32 * LDP];
    __shared__ float red[4];
    const int tid = threadIdx.x;
    const int bi = blockIdx.x;

    if (bi < 256) {
        const int mt = bi & 7, nt = (bi >> 3) & 3, ks = bi >> 5;
        const int b0 = mt * 64, d0 = nt * 64, kc = ks * 128;
        const int sm = tid >> 3, sk4 = (tid & 7) * 4;
        const int ty4 = (tid >> 4) * 4, tx4 = (tid & 15) * 4;
        float acc[4][4] = {};
        for (int kt = 0; kt < 128; kt += 32) {
            const int kg = kc + kt;
            #pragma unroll
            for (int pass = 0; pass < 2; ++pass) {
                int m = sm + pass * 32;
                float4 av = *reinterpret_cast<const float4*>(&hg[(b0 + m) * DG + kg + sk4]);
                sA[(sk4 + 0) * LDP + m] = av.x; sA[(sk4 + 1) * LDP + m] = av.y;
                sA[(sk4 + 2) * LDP + m] = av.z; sA[(sk4 + 3) * LDP + m] = av.w;
                float4 wv4 = *reinterpret_cast<const float4*>(&Wq[(d0 + m) * DG + kg + sk4]);
                sB[(sk4 + 0) * LDP + m] = wv4.x; sB[(sk4 + 1) * LDP + m] = wv4.y;
                sB[(sk4 + 2) * LDP + m] = wv4.z; sB[(sk4 + 3) * LDP + m] = wv4.w;
            }
            __syncthreads();
            #pragma unroll
            for (int kk = 0; kk < 32; ++kk) {
                float4 a4 = *reinterpret_cast<const float4*>(&sA[kk * LDP + ty4]);
                float4 b4 = *reinterpret_cast<const float4*>(&sB[kk * LDP + tx4]);
                FMA16(a4, b4, acc)
            }
            __syncthreads();
        }
        float* outp = qp + ks * (B * DA);
        #pragma unroll
        for (int i = 0; i < 4; ++i) {
            float4 o = make_float4(acc[i][0], acc[i][1], acc[i][2], acc[i][3]);
            *reinterpret_cast<float4*>(&outp[(b0 + ty4 + i) * DA + d0 + tx4]) = o;
        }
    } else if (bi < 320) {
        const int b2 = bi - 256;
        const int e0 = (b2 & 7) * 32, f0 = (b2 >> 3) * 32;
        const int col = tid & 31, row8 = tid >> 5;
        #pragma unroll
        for (int pass = 0; pass < 4; ++pass) {
            int r = row8 + pass * 8;
            sA[r * 33 + col] = Uq[(e0 + r) * DA + f0 + col];
        }
        __syncthreads();
        #pragma unroll
        for (int pass = 0; pass < 4; ++pass) {
            int r = row8 + pass * 8;
            UqT[(f0 + r) * DA + e0 + col] = sA[col * 33 + r];
        }
    } else {
        const int p = bi - 320, d = tid;
        const float inv = 1.0f / DA;
        float ek = Ek[p * DA + d], ev = Ev[p * DA + d];
        float wkd = wk[d], wvd = wv[d];
        float ck = bk[d] + ek, cv = bv[d] + ev;

        float Sck  = block_reduce_sum(ck, red);
        float Sck2 = block_reduce_sum(ck * ck, red);
        float Swck = block_reduce_sum(wkd * ck, red);
        float Scv  = block_reduce_sum(cv, red);
        float Scv2 = block_reduce_sum(cv * cv, red);
        float Swcv = block_reduce_sum(wvd * cv, red);
        float Swk  = block_reduce_sum(wkd, red);
        float Swv  = block_reduce_sum(wvd, red);

        float mwk = Swk * inv, mwv = Swv * inv;
        float mck = Sck * inv, mcv = Scv * inv;
        if (d == 0) {
            pst[0 * P + p] = mck;
            pst[1 * P + p] = Swck * inv - mwk * mck;  // Bk
            pst[2 * P + p] = Sck2 * inv - mck * mck;  // Ck
            pst[3 * P + p] = mcv;
            pst[4 * P + p] = Swcv * inv - mwv * mcv;  // Bv
            pst[5 * P + p] = Scv2 * inv - mcv * mcv;  // Cv
        }
        if (p == 0) {
            float Swk2 = block_reduce_sum(wkd * wkd, red);
            float Swv2 = block_reduce_sum(wvd * wvd, red);
            if (d == 0) {
                scal4[0] = mwk;
                scal4[1] = Swk2 * inv - mwk * mwk;   // A_k
                scal4[2] = mwv;
                scal4[3] = Swv2 * inv - mwv * mwv;   // A_v
            }
        }
    }
}

// ---------------------------------------------------------------- KC: per-b reduce qp -> LN -> q2=q@Uq^T -> r=q2@Vk -> gr + 4 scalars
__global__ __launch_bounds__(256) void KC(const float* __restrict__ qp, const float* __restrict__ bq,
                                          const float* __restrict__ gq, const float* __restrict__ bqln,
                                          const float* __restrict__ UqT, const float* __restrict__ Vk,
                                          const float* __restrict__ gk,
                                          const float* __restrict__ wk, const float* __restrict__ bk,
                                          const float* __restrict__ bkln,
                                          float* __restrict__ gr, float* __restrict__ bscal) {
    __shared__ __align__(16) float q_lds[DA];
    __shared__ __align__(16) float q2_lds[DA];
    __shared__ float red[4];
    const int b = blockIdx.x, d = threadIdx.x;
    float x = bq[d];
    #pragma unroll
    for (int ks = 0; ks < 8; ++ks) x += qp[ks * (B * DA) + b * DA + d];
    float mu = block_reduce_sum(x, red) * (1.0f / DA);
    float xc = x - mu;
    float var = block_reduce_sum(xc * xc, red) * (1.0f / DA);
    float qv = xc * rsqrtf(var + 1e-5f) * gq[d] + bqln[d];
    q_lds[d] = qv;
    __syncthreads();

    float q2 = 0.f;
    for (int f = 0; f < DA; f += 4) {
        float4 qf = *reinterpret_cast<const float4*>(&q_lds[f]);
        q2 = fmaf(qf.x, UqT[(f + 0) * DA + d], q2);
        q2 = fmaf(qf.y, UqT[(f + 1) * DA + d], q2);
        q2 = fmaf(qf.z, UqT[(f + 2) * DA + d], q2);
        q2 = fmaf(qf.w, UqT[(f + 3) * DA + d], q2);
    }
    q2_lds[d] = q2;
    __syncthreads();

    float r = 0.f;
    for (int e = 0; e < DA; e += 4) {
        float4 qe = *reinterpret_cast<const float4*>(&q2_lds[e]);
        r = fmaf(qe.x, Vk[(e + 0) * DA + d], r);
        r = fmaf(qe.y, Vk[(e + 1) * DA + d], r);
        r = fmaf(qe.z, Vk[(e + 2) * DA + d], r);
        r = fmaf(qe.w, Vk[(e + 3) * DA + d], r);
    }
    float grv = gk[d] * r;
    gr[b * DA + d] = grv;

    float Wg = block_reduce_sum(wk[d] * grv, red);
    float Cg = block_reduce_sum(bk[d] * grv, red);
    float G  = block_reduce_sum(grv, red);
    float Bb = block_reduce_sum(bkln[d] * r, red);
    if (d == 0) {
        bscal[b] = Wg; bscal[B + b] = Cg; bscal[2 * B + b] = G; bscal[3 * B + b] = Bb;
    }
}

// ---------------------------------------------------------------- KD: epart[ks] = gr @ Ek^T partial (512x1024, K-chunk 128, KS=2)
__global__ __launch_bounds__(256) void KD(const float* __restrict__ gr, const float* __restrict__ Ek,
                                          float* __restrict__ epart) {
    __shared__ __align__(16) float sA[32 * LDP];
    __shared__ __align__(16) float sB[32 * LDP];
    const int tid = threadIdx.x, bi = blockIdx.x;
    const int mt = bi & 7, nt = (bi >> 3) & 15, ks = bi >> 7;
    const int b0 = mt * 64, p0 = nt * 64, kc = ks * 128;
    const int sm = tid >> 3, sk4 = (tid & 7) * 4;
    const int ty4 = (tid >> 4) * 4, tx4 = (tid & 15) * 4;
    float acc[4][4] = {};
    for (int kt = 0; kt < 128; kt += 32) {
        const int kg = kc + kt;
        #pragma unroll
        for (int pass = 0; pass < 2; ++pass) {
            int m = sm + pass * 32;
            float4 av = *reinterpret_cast<const float4*>(&gr[(b0 + m) * DA + kg + sk4]);
            sA[(sk4 + 0) * LDP + m] = av.x; sA[(sk4 + 1) * LDP + m] = av.y;
            sA[(sk4 + 2) * LDP + m] = av.z; sA[(sk4 + 3) * LDP + m] = av.w;
            float4 ev = *reinterpret_cast<const float4*>(&Ek[(p0 + m) * DA + kg + sk4]);
            sB[(sk4 + 0) * LDP + m] = ev.x; sB[(sk4 + 1) * LDP + m] = ev.y;
            sB[(sk4 + 2) * LDP + m] = ev.z; sB[(sk4 + 3) * LDP + m] = ev.w;
        }
        __syncthreads();
        #pragma unroll
        for (int kk = 0; kk < 32; ++kk) {
            float4 a4 = *reinterpret_cast<const float4*>(&sA[kk * LDP + ty4]);
            float4 b4 = *reinterpret_cast<const float4*>(&sB[kk * LDP + tx4]);
            FMA16(a4, b4, acc)
        }
        __syncthreads();
    }
    float* outp = epart + ks * (B * P);
    #pragma unroll
    for (int i = 0; i < 4; ++i) {
        float4 o = make_float4(acc[i][0], acc[i][1], acc[i][2], acc[i][3]);
        *reinterpret_cast<float4*>(&outp[(b0 + ty4 + i) * P + p0 + tx4]) = o;
    }
}

// ---------------------------------------------------------------- KE: sum epart -> e -> u -> rowsum -> alpha (out), beta, c-base (out)
__global__ __launch_bounds__(256) void KE(const float* __restrict__ epart, const float* __restrict__ desc,
                                          const float* __restrict__ bscal, const float* __restrict__ pst,
                                          const float* __restrict__ scal4,
                                          const float* __restrict__ gv, const float* __restrict__ wv,
                                          const float* __restrict__ bvv, const float* __restrict__ bvln,
                                          float* __restrict__ alpha_out, float* beta,
                                          float* __restrict__ out_c) {
    __shared__ float red[4];
    const int b = blockIdx.x, tid = threadIdx.x;
    const float mwk = scal4[0], Ak = scal4[1], mwv = scal4[2], Av = scal4[3];
    const float Wg = bscal[b], Cg = bscal[B + b], G = bscal[2 * B + b], Bb = bscal[3 * B + b];
    float u[4], sv[4];
    float usum = 0.f;
    #pragma unroll
    for (int j = 0; j < 4; ++j) {
        int p = j * 256 + tid;
        float dot = epart[b * P + p] + epart[B * P + b * P + p];
        float s = desc[b * P + p];
        float mck = pst[p], Bk = pst[P + p], Ck = pst[2 * P + p];
        float var = fmaf(s, fmaf(s, Ak, 2.0f * Bk), Ck);
        float rstd = rsqrtf(var + 1e-5f);
        float mu = fmaf(s, mwk, mck);
        float e = (rstd * (fmaf(s, Wg, Cg) + dot - mu * G) + Bb) * 0.0625f;
        float uu = 1.0f / (1.0f + expf(-e));
        u[j] = uu; sv[j] = s; usum += uu;
    }
    float S = block_reduce_sum(usum, red);   // syncthreads inside: all epart loads done before beta writes
    float invS = 1.0f / (S + 1e-12f);
    float T = S * invS;
    float SB = 0.f, SBs = 0.f, SBm = 0.f;
    #pragma unroll
    for (int j = 0; j < 4; ++j) {
        int p = j * 256 + tid;
        float a = u[j] * invS;
        alpha_out[b * P + p] = a;
        float s = sv[j];
        float mcv = pst[3 * P + p], Bv = pst[4 * P + p], Cv = pst[5 * P + p];
        float var = fmaf(s, fmaf(s, Av, 2.0f * Bv), Cv);
        float rv = rsqrtf(var + 1e-5f);
        float bt = a * rv;
        beta[b * P + p] = bt;
        SB += bt;
        SBs = fmaf(bt, s, SBs);
        SBm = fmaf(bt, fmaf(s, mwv, mcv), SBm);
    }
    SB  = block_reduce_sum(SB, red);
    SBs = block_reduce_sum(SBs, red);
    SBm = block_reduce_sum(SBm, red);
    out_c[b * DA + tid] = gv[tid] * (wv[tid] * SBs + bvv[tid] * SB - SBm) + bvln[tid] * T;
}

// ---------------------------------------------------------------- KF: cpart[ks] = beta @ Ev partial (512x256, K-chunk 128, KS=8)
__global__ __launch_bounds__(256) void KF(const float* __restrict__ beta, const float* __restrict__ Ev,
                                          float* __restrict__ cpart) {
    __shared__ __align__(16) float sA[32 * LDP];
    __shared__ __align__(16) float sB[32 * LDP];
    const int tid = threadIdx.x, bi = blockIdx.x;
    const int mt = bi & 7, nt = (bi >> 3) & 3, ks = bi >> 5;
    const int b0 = mt * 64, d0 = nt * 64, kc = ks * 128;
    const int sm = tid >> 3, sk4 = (tid & 7) * 4;
    const int kr = tid >> 4, n4 = (tid & 15) * 4;
    const int ty4 = (tid >> 4) * 4, tx4 = (tid & 15) * 4;
    float acc[4][4] = {};
    for (int kt = 0; kt < 128; kt += 32) {
        const int kg = kc + kt;
        #pragma unroll
        for (int pass = 0; pass < 2; ++pass) {
            int m = sm + pass * 32;
            float4 av = *reinterpret_cast<const float4*>(&beta[(b0 + m) * P + kg + sk4]);
            sA[(sk4 + 0) * LDP + m] = av.x; sA[(sk4 + 1) * LDP + m] = av.y;
            sA[(sk4 + 2) * LDP + m] = av.z; sA[(sk4 + 3) * LDP + m] = av.w;
            int k = kr + pass * 16;
            *reinterpret_cast<float4*>(&sB[k * LDP + n4]) =
                *reinterpret_cast<const float4*>(&Ev[(kg + k) * DA + d0 + n4]);
        }
        __syncthreads();
        #pragma unroll
        for (int kk = 0; kk < 32; ++kk) {
            float4 a4 = *reinterpret_cast<const float4*>(&sA[kk * LDP + ty4]);
            float4 b4 = *reinterpret_cast<const float4*>(&sB[kk * LDP + tx4]);
            FMA16(a4, b4, acc)
        }
        __syncthreads();
    }
    float* outp = cpart + ks * (B * DA);
    #pragma unroll
    for (int i = 0; i < 4; ++i) {
        float4 o = make_float4(acc[i][0], acc[i][1], acc[i][2], acc[i][3]);
        *reinterpret_cast<float4*>(&outp[(b0 + ty4 + i) * DA + d0 + tx4]) = o;
    }
}

// ---------------------------------------------------------------- KG: out_c += gv * sum_ks cpart
__global__ __launch_bounds__(256) void KG(const float* __restrict__ cpart, const float* __restrict__ gv,
                                          float* __restrict__ out_c) {
    const int b = blockIdx.x, d = threadIdx.x;
    float s = 0.f;
    #pragma unroll
    for (int ks = 0; ks < 8; ++ks) s += cpart[ks * (B * DA) + b * DA + d];
    out_c[b * DA + d] = fmaf(gv[d], s, out_c[b * DA + d]);
}

// ---------------------------------------------------------------- launch
extern "C" void kernel_launch(void* const* d_in, const int* in_sizes, int n_in,
                              void* d_out, int out_size, void* d_ws, size_t ws_size,
                              hipStream_t stream) {
    (void)in_sizes; (void)n_in; (void)out_size; (void)ws_size;
    const float* hg   = (const float*)d_in[0];
    const float* desc = (const float*)d_in[1];
    const float* Wq   = (const float*)d_in[2];
    const float* bq   = (const float*)d_in[3];
    const float* wk   = (const float*)d_in[4];
    const float* bk   = (const float*)d_in[5];
    const float* wv   = (const float*)d_in[6];
    const float* bv   = (const float*)d_in[7];
    const float* Ek   = (const float*)d_in[8];
    const float* Ev   = (const float*)d_in[9];
    const float* Uq   = (const float*)d_in[10];
    const float* Vk   = (const float*)d_in[11];
    const float* gq   = (const float*)d_in[12];
    const float* bqln = (const float*)d_in[13];
    const float* gk   = (const float*)d_in[14];
    const float* bkln = (const float*)d_in[15];
    const float* gv   = (const float*)d_in[16];
    const float* bvln = (const float*)d_in[17];

    float* out = (float*)d_out;
    float* out_c = out;              // B*DA
    float* out_alpha = out + B * DA; // B*P

    // ws timeline-aliased layout (floats), high-water 1,581,060 floats ~= 6.03 MB:
    //   [0, 1048576)        qp[8][B][DA]   (KA->KC)
    //                       epart[2][B][P] (KD->KE)  over dead qp
    //   [0, 524288)         beta[B][P]     (KE->KF)  over dead epart0 (per-thread RAW-safe)
    //   [1048576, 1179648)  gr[B][DA]      (KC->KD)
    //   [1179648, 1245184)  UqT[DA][DA]    (KA->KC)
    //   [524288, 1572864)   cpart[8][B][DA](KF->KG)  over dead epart1/gr/UqT
    //   [1572864, ...)      bscal, pst, scal4
    float* ws = (float*)d_ws;
    float* qp    = ws;
    float* epart = ws;
    float* beta  = ws;
    float* gr    = ws + 1048576;
    float* UqT   = ws + 1179648;
    float* cpart = ws + 524288;
    float* bscal = ws + 1572864;
    float* pst   = ws + 1574912;
    float* scal4 = ws + 1581056;

    KA<<<1344, 256, 0, stream>>>(hg, Wq, Uq, Ek, Ev, wk, bk, wv, bv, qp, UqT, pst, scal4);
    KC<<<512, 256, 0, stream>>>(qp, bq, gq, bqln, UqT, Vk, gk, wk, bk, bkln, gr, bscal);
    KD<<<256, 256, 0, stream>>>(gr, Ek, epart);
    KE<<<512, 256, 0, stream>>>(epart, desc, bscal, pst, scal4, gv, wv, bv, bvln, out_alpha, beta, out_c);
    KF<<<256, 256, 0, stream>>>(beta, Ev, cpart);
    KG<<<512, 256, 0, stream>>>(cpart, gv, out_c);
}